// Round 3
// baseline (244.685 us; speedup 1.0000x reference)
//
#include <hip/hip_runtime.h>
#include <math.h>

#define B 256
#define D 512
#define S 196
#define SQ 49    // float4 quads per 196-float row
#define NCH 8

// ---------------- K1: full p-vector. Grid 256 = 32 batch-octets x 8 d-chunks.
// p[b,d] = mem[b,d] * (sum_e u[b,e] * W[e,d]) + u[b,d],  u = ctrl*w_attn.
// Each block reads its 512x64 W column-panel (128 KB) ONCE for 8 batches
// -> aggregate W traffic 32 MB L2 (vs 256 MB for per-(b,c)-block panels).
// b_concat is softmax-shift-invariant -> dropped.
__global__ __launch_bounds__(256) void k_pvec(
    const float* __restrict__ mem, const float* __restrict__ ctrl,
    const float* __restrict__ w_attn, const float* __restrict__ W,
    float* __restrict__ p) {
    __shared__ float u_s[8][D];                // 16 KB
    const int c = blockIdx.x & 7;              // d-chunk
    const int b0 = (blockIdx.x >> 3) * 8;      // batch octet
    const int t = threadIdx.x;
    // stage u for 8 batches (coalesced: 256 consecutive e per row)
#pragma unroll
    for (int idx = t; idx < 8 * D; idx += 256) {
        const int j = idx >> 9, e = idx & (D - 1);
        u_s[j][e] = ctrl[(size_t)(b0 + j) * D + e] * w_attn[e];
    }
    __syncthreads();
    const int d = t & 63;                      // lane's d within chunk
    const int j0 = (t >> 6) * 2, j1 = j0 + 1;  // this thread's 2 batches
    const float* wcol = W + (size_t)c * 64 + d;
    float a0 = 0.f, a1 = 0.f;
#pragma unroll 4
    for (int e = 0; e < D; ++e) {
        const float wv = wcol[(size_t)e * D];  // 256B coalesced per warp
        a0 += u_s[j0][e] * wv;                 // LDS broadcast (conflict-free)
        a1 += u_s[j1][e] * wv;
    }
    const int dg = c * 64 + d;
    p[(size_t)(b0 + j0) * D + dg] =
        mem[(size_t)(b0 + j0) * D + dg] * a0 + u_s[j0][dg];
    p[(size_t)(b0 + j1) * D + dg] =
        mem[(size_t)(b0 + j1) * D + dg] * a1 + u_s[j1][dg];
}

// ---------------- K2: partial logits. Grid B*8 = 2048 blocks x 256 thr.
// Head is now a single 256B p load -> the kb HBM stream starts immediately
// (R1's per-block 128KB W-panel prologue burst is gone). Body: wave w
// streams 16 rows as two independent load chains (50KB/CU in flight at
// 8 blocks/CU > the ~22KB Little's-law requirement for 6.3 TB/s).
__global__ __launch_bounds__(256, 8) void k_logits(
    const float* __restrict__ kb, const float* __restrict__ p,
    float* __restrict__ rai_part) {
    __shared__ float p_s[64];
    __shared__ float part[4][S];
    const int bid = blockIdx.x;
    const int b = bid >> 3, c = bid & 7;
    const int t = threadIdx.x;
    const int w = t >> 6, l = t & 63;
    if (t < 64) p_s[t] = p[(size_t)b * D + c * 64 + t];
    __syncthreads();
    const float* base = kb + (size_t)b * D * S + (size_t)c * 64 * S;
    if (l < SQ) {
        float4 acc0 = {0.f, 0.f, 0.f, 0.f}, acc1 = {0.f, 0.f, 0.f, 0.f};
        for (int i = 0; i < 8; ++i) {
            const int r0 = w * 16 + i, r1 = w * 16 + 8 + i;
            const float4 v0 = *(const float4*)(base + (size_t)r0 * S + 4 * l);
            const float4 v1 = *(const float4*)(base + (size_t)r1 * S + 4 * l);
            const float pv0 = p_s[r0], pv1 = p_s[r1];
            acc0.x += pv0 * v0.x; acc0.y += pv0 * v0.y;
            acc0.z += pv0 * v0.z; acc0.w += pv0 * v0.w;
            acc1.x += pv1 * v1.x; acc1.y += pv1 * v1.y;
            acc1.z += pv1 * v1.z; acc1.w += pv1 * v1.w;
        }
        part[w][4 * l + 0] = acc0.x + acc1.x;
        part[w][4 * l + 1] = acc0.y + acc1.y;
        part[w][4 * l + 2] = acc0.z + acc1.z;
        part[w][4 * l + 3] = acc0.w + acc1.w;
    }
    __syncthreads();
    if (t < S)
        rai_part[(size_t)bid * S + t] =
            (part[0][t] + part[1][t]) + (part[2][t] + part[3][t]);
}

// ---------------- K3: softmax head + weighted sum. Grid 2048 x 256.
// Head: redundant (cheap, L2-hot) softmax from the 8 rai partials.
// Body: per-lane row partials -> [64][49] LDS tile (odd stride -> <=2-way
// bank aliasing = free), one transpose-reduce phase, coalesced 256B store.
// kb re-read is L3-resident.
__global__ __launch_bounds__(256, 8) void k_wsum(
    const float* __restrict__ kb, const float* __restrict__ rai_part,
    float* __restrict__ out) {
    __shared__ float rvi_s[S];
    __shared__ float redm[4], reds[4];
    __shared__ float plds[64 * SQ];   // 12.5 KB
    __shared__ float red2[4][64];     // 1 KB
    const int bid = blockIdx.x;
    const int b = bid >> 3, c = bid & 7;
    const int t = threadIdx.x;
    const int w = t >> 6, l = t & 63;

    float rai = -INFINITY;
    if (t < S) {
        float v = 0.f;
#pragma unroll
        for (int k = 0; k < NCH; ++k)
            v += rai_part[((size_t)b * NCH + k) * S + t];
        rai = v;
    }
    float m = rai;
#pragma unroll
    for (int o = 1; o < 64; o <<= 1) m = fmaxf(m, __shfl_xor(m, o, 64));
    if (l == 0) redm[w] = m;
    __syncthreads();
    m = fmaxf(fmaxf(redm[0], redm[1]), fmaxf(redm[2], redm[3]));
    float ex = (t < S) ? __expf(rai - m) : 0.f;
    float sm = ex;
#pragma unroll
    for (int o = 1; o < 64; o <<= 1) sm += __shfl_xor(sm, o, 64);
    if (l == 0) reds[w] = sm;
    __syncthreads();
    const float li = (reds[0] + reds[1]) + (reds[2] + reds[3]);
    if (t < S) rvi_s[t] = ex / li;
    __syncthreads();

    float4 rv = {0.f, 0.f, 0.f, 0.f};
    if (l < SQ) rv = *(const float4*)&rvi_s[4 * l];
    const float* base = kb + (size_t)b * D * S + (size_t)c * 64 * S;
    if (l < SQ) {
#pragma unroll 2
        for (int i = 0; i < 8; ++i) {
            const int r0 = w * 16 + i, r1 = w * 16 + 8 + i;
            const float4 v0 = *(const float4*)(base + (size_t)r0 * S + 4 * l);
            const float4 v1 = *(const float4*)(base + (size_t)r1 * S + 4 * l);
            plds[r0 * SQ + l] =
                rv.x * v0.x + rv.y * v0.y + rv.z * v0.z + rv.w * v0.w;
            plds[r1 * SQ + l] =
                rv.x * v1.x + rv.y * v1.y + rv.z * v1.z + rv.w * v1.w;
        }
    }
    __syncthreads();
    {   // transpose-reduce: thread (seg,row) sums its 12-13 quad partials
        const int row = t & 63, seg = t >> 6;
        const int j0 = (seg * SQ) >> 2, j1 = ((seg + 1) * SQ) >> 2;
        float a = 0.f;
        for (int j = j0; j < j1; ++j) a += plds[row * SQ + j];
        red2[seg][row] = a;
    }
    __syncthreads();
    if (t < 64)
        out[(size_t)b * D + c * 64 + t] =
            (red2[0][t] + red2[1][t]) + (red2[2][t] + red2[3][t]);
}

extern "C" void kernel_launch(void* const* d_in, const int* in_sizes, int n_in,
                              void* d_out, int out_size, void* d_ws, size_t ws_size,
                              hipStream_t stream) {
    const float* mem  = (const float*)d_in[0];  // [B, d]
    const float* ctrl = (const float*)d_in[1];  // [B, d]
    const float* kb   = (const float*)d_in[2];  // [B, d, S]
    const float* W    = (const float*)d_in[3];  // [d, d]
    // d_in[4] = b_concat: softmax-shift-invariant, unused
    const float* wat  = (const float*)d_in[5];  // [d]
    float* out = (float*)d_out;                 // [B, d]

    float* p        = (float*)d_ws;             // B*D*4 = 0.5 MB
    float* rai_part = p + (size_t)B * D;        // 2048*S*4 = 1.6 MB

    k_pvec  <<<256,     256, 0, stream>>>(mem, ctrl, wat, W, p);
    k_logits<<<B * NCH, 256, 0, stream>>>(kb, p, rai_part);
    k_wsum  <<<B * NCH, 256, 0, stream>>>(kb, rai_part, out);
}

// Round 4
// 182.528 us; speedup vs baseline: 1.3405x; 1.3405x over previous
//
#include <hip/hip_runtime.h>
#include <math.h>

#define B 256
#define D 512
#define S 196
#define SQ 49    // float4 quads per 196-float row
#define NCH 8

// ---------------- K1: partial GEMM. Grid 512 = (ce 0..7) x (dhalf 0..1) x
// (batch-octet 0..31), 2 blocks/CU. gpart[(b*8+ce)*D + d] =
// sum_{e in chunk ce} u[b,e]*W[e,d], u = ctrl*w_attn. Each W element read
// once per 8 batches (32 MB aggregate). 64 e-iters/thread (k_pvec's 512-long
// serial chain at 1 block/CU was 69.7 us; this was ~13 us in R0, halved work
// per block + 2 blocks/CU should land ~5 us).
__global__ __launch_bounds__(256) void k_gemm2(
    const float* __restrict__ ctrl, const float* __restrict__ w_attn,
    const float* __restrict__ W, float* __restrict__ gpart) {
    __shared__ float u_s[64][8];          // [e_local][batch j]
    const int ce = blockIdx.x >> 6;       // e-chunk 0..7
    const int dh = (blockIdx.x >> 5) & 1; // d half
    const int b0 = (blockIdx.x & 31) * 8; // batch octet
    const int t = threadIdx.x;
    const int d = dh * 256 + t;
#pragma unroll
    for (int k = t; k < 512; k += 256) {
        const int j = k & 7, el = k >> 3;
        const int e = ce * 64 + el;
        u_s[el][j] = ctrl[(size_t)(b0 + j) * D + e] * w_attn[e];
    }
    __syncthreads();
    float a[8];
#pragma unroll
    for (int j = 0; j < 8; ++j) a[j] = 0.f;
    for (int e0 = 0; e0 < 64; e0 += 4) {
        float wv[4];
#pragma unroll
        for (int i = 0; i < 4; ++i)
            wv[i] = W[(size_t)(ce * 64 + e0 + i) * D + d];
#pragma unroll
        for (int i = 0; i < 4; ++i) {
            const float4 ua = *(const float4*)&u_s[e0 + i][0];
            const float4 ub = *(const float4*)&u_s[e0 + i][4];
            a[0] += ua.x * wv[i]; a[1] += ua.y * wv[i];
            a[2] += ua.z * wv[i]; a[3] += ua.w * wv[i];
            a[4] += ub.x * wv[i]; a[5] += ub.y * wv[i];
            a[6] += ub.z * wv[i]; a[7] += ub.w * wv[i];
        }
    }
#pragma unroll
    for (int j = 0; j < 8; ++j)
        gpart[((size_t)(b0 + j) * NCH + ce) * D + d] = a[j];
}

// ---------------- K2: ONE block per batch (grid 256 = 1/CU exact, 1024 thr
// = 16 waves). Replaces old K2+K3: rai is complete block-locally, so the
// softmax needs no cross-block round-trip, no redundant 8x recompute, no
// third launch, and pass 2 re-reads kb[b] while it is still cache-hot.
// Pass 1: p head (b_concat softmax-shift-invariant, dropped) + full rai[196]
//         via 16 wave-partials (each wave streams 32 rows, 2 load chains).
// Pass 2: out[d] = sum_s rvi[s]*kb[d,s]; per-row lane partials -> [256][49]
//         LDS tile (odd stride -> <=2-way bank alias = free), transpose-
//         reduce, coalesced 1KB stores. Two 256-row halves reuse the tile.
struct SmP2 { float plds[256 * SQ]; float red2[4][256]; };  // 54.2 KB
__global__ __launch_bounds__(1024, 1) void k_batch(
    const float* __restrict__ kb, const float* __restrict__ gpart,
    const float* __restrict__ mem, const float* __restrict__ ctrl,
    const float* __restrict__ w_attn, float* __restrict__ out) {
    __shared__ float p_s[D];            // 2 KB
    __shared__ float rvi_s[S];
    __shared__ float redm[4], reds[4];
    __shared__ union { float part[16][S]; SmP2 p2; } smu;  // 54.2 KB
    const int b = blockIdx.x;
    const int t = threadIdx.x;
    const int w = t >> 6, l = t & 63;
    const float* base = kb + (size_t)b * D * S;

    // ---- p head
    if (t < D) {
        float s = 0.f;
#pragma unroll
        for (int ce = 0; ce < NCH; ++ce)
            s += gpart[((size_t)b * NCH + ce) * D + t];
        p_s[t] = mem[(size_t)b * D + t] * s +
                 ctrl[(size_t)b * D + t] * w_attn[t];
    }
    __syncthreads();

    // ---- pass 1: wave w streams rows w*32..w*32+31 (2 chains)
    if (l < SQ) {
        float4 acc0 = {0.f, 0.f, 0.f, 0.f}, acc1 = {0.f, 0.f, 0.f, 0.f};
        for (int i = 0; i < 16; ++i) {
            const int r0 = w * 32 + i, r1 = w * 32 + 16 + i;
            const float4 v0 = *(const float4*)(base + (size_t)r0 * S + 4 * l);
            const float4 v1 = *(const float4*)(base + (size_t)r1 * S + 4 * l);
            const float pv0 = p_s[r0], pv1 = p_s[r1];
            acc0.x += pv0 * v0.x; acc0.y += pv0 * v0.y;
            acc0.z += pv0 * v0.z; acc0.w += pv0 * v0.w;
            acc1.x += pv1 * v1.x; acc1.y += pv1 * v1.y;
            acc1.z += pv1 * v1.z; acc1.w += pv1 * v1.w;
        }
        smu.part[w][4 * l + 0] = acc0.x + acc1.x;
        smu.part[w][4 * l + 1] = acc0.y + acc1.y;
        smu.part[w][4 * l + 2] = acc0.z + acc1.z;
        smu.part[w][4 * l + 3] = acc0.w + acc1.w;
    }
    __syncthreads();

    // ---- rai reduce + softmax (first 4 waves active; barriers block-wide)
    float rai = -INFINITY, ex = 0.f;
    if (t < S) {
        float v = 0.f;
#pragma unroll
        for (int ww = 0; ww < 16; ++ww) v += smu.part[ww][t];
        rai = v;
    }
    if (t < 256) {
        float m = rai;
#pragma unroll
        for (int o = 1; o < 64; o <<= 1) m = fmaxf(m, __shfl_xor(m, o, 64));
        if (l == 0) redm[w] = m;
    }
    __syncthreads();
    if (t < 256) {
        const float m = fmaxf(fmaxf(redm[0], redm[1]), fmaxf(redm[2], redm[3]));
        ex = (t < S) ? __expf(rai - m) : 0.f;
        float sm = ex;
#pragma unroll
        for (int o = 1; o < 64; o <<= 1) sm += __shfl_xor(sm, o, 64);
        if (l == 0) reds[w] = sm;
    }
    __syncthreads();
    if (t < S) {
        const float li = (reds[0] + reds[1]) + (reds[2] + reds[3]);
        rvi_s[t] = ex / li;
    }
    __syncthreads();   // also fences union: part reads done before plds writes

    // ---- pass 2: cache-hot re-read, two 256-row halves
    float4 rv = {0.f, 0.f, 0.f, 0.f};
    if (l < SQ) rv = *(const float4*)&rvi_s[4 * l];
    for (int half = 0; half < 2; ++half) {
        const int rb = half * 256;
        if (l < SQ) {
#pragma unroll 2
            for (int i = 0; i < 8; ++i) {
                const int q0 = w * 16 + i, q1 = w * 16 + 8 + i;
                const float4 v0 =
                    *(const float4*)(base + (size_t)(rb + q0) * S + 4 * l);
                const float4 v1 =
                    *(const float4*)(base + (size_t)(rb + q1) * S + 4 * l);
                smu.p2.plds[q0 * SQ + l] =
                    rv.x * v0.x + rv.y * v0.y + rv.z * v0.z + rv.w * v0.w;
                smu.p2.plds[q1 * SQ + l] =
                    rv.x * v1.x + rv.y * v1.y + rv.z * v1.z + rv.w * v1.w;
            }
        }
        __syncthreads();
        {   // transpose-reduce: 1024 thr = 256 rows x 4 segs of 12-13 quads
            const int r = t & 255, seg = t >> 8;
            const int j0 = (seg * SQ) >> 2, j1 = ((seg + 1) * SQ) >> 2;
            float a = 0.f;
            for (int j = j0; j < j1; ++j) a += smu.p2.plds[r * SQ + j];
            smu.p2.red2[seg][r] = a;
        }
        __syncthreads();
        if (t < 256)
            out[(size_t)b * D + rb + t] =
                (smu.p2.red2[0][t] + smu.p2.red2[1][t]) +
                (smu.p2.red2[2][t] + smu.p2.red2[3][t]);
        __syncthreads();
    }
}

extern "C" void kernel_launch(void* const* d_in, const int* in_sizes, int n_in,
                              void* d_out, int out_size, void* d_ws, size_t ws_size,
                              hipStream_t stream) {
    const float* mem  = (const float*)d_in[0];  // [B, d]
    const float* ctrl = (const float*)d_in[1];  // [B, d]
    const float* kb   = (const float*)d_in[2];  // [B, d, S]
    const float* W    = (const float*)d_in[3];  // [d, d]
    // d_in[4] = b_concat: softmax-shift-invariant, unused
    const float* wat  = (const float*)d_in[5];  // [d]
    float* out = (float*)d_out;                 // [B, d]

    float* gpart = (float*)d_ws;                // B*8*D*4 = 4 MB

    k_gemm2<<<512, 256,  0, stream>>>(ctrl, wat, W, gpart);
    k_batch<<<B,   1024, 0, stream>>>(kb, gpart, mem, ctrl, wat, out);
}

// Round 5
// 178.513 us; speedup vs baseline: 1.3707x; 1.0225x over previous
//
#include <hip/hip_runtime.h>
#include <math.h>

#define B 256
#define D 512
#define S 196
#define NCH 8
#define TC 16    // tile columns (64 B, row-stride 784 B keeps float4 aligned)
#define NT 13    // ceil(196/16)

// ---------------- K1: partial GEMM (unchanged from R4, ~5-6 us).
// Grid 512 = (ce 0..7) x (dhalf 0..1) x (batch-octet 0..31), 2 blocks/CU.
// gpart[(b*8+ce)*D + d] = sum_{e in chunk ce} u[b,e]*W[e,d], u = ctrl*w_attn.
// Each W element read once per 8 batches (32 MB aggregate L2).
__global__ __launch_bounds__(256) void k_gemm2(
    const float* __restrict__ ctrl, const float* __restrict__ w_attn,
    const float* __restrict__ W, float* __restrict__ gpart) {
    __shared__ float u_s[64][8];          // [e_local][batch j]
    const int ce = blockIdx.x >> 6;       // e-chunk 0..7
    const int dh = (blockIdx.x >> 5) & 1; // d half
    const int b0 = (blockIdx.x & 31) * 8; // batch octet
    const int t = threadIdx.x;
    const int d = dh * 256 + t;
#pragma unroll
    for (int k = t; k < 512; k += 256) {
        const int j = k & 7, el = k >> 3;
        const int e = ce * 64 + el;
        u_s[el][j] = ctrl[(size_t)(b0 + j) * D + e] * w_attn[e];
    }
    __syncthreads();
    float a[8];
#pragma unroll
    for (int j = 0; j < 8; ++j) a[j] = 0.f;
    for (int e0 = 0; e0 < 64; e0 += 4) {
        float wv[4];
#pragma unroll
        for (int i = 0; i < 4; ++i)
            wv[i] = W[(size_t)(ce * 64 + e0 + i) * D + d];
#pragma unroll
        for (int i = 0; i < 4; ++i) {
            const float4 ua = *(const float4*)&u_s[e0 + i][0];
            const float4 ub = *(const float4*)&u_s[e0 + i][4];
            a[0] += ua.x * wv[i]; a[1] += ua.y * wv[i];
            a[2] += ua.z * wv[i]; a[3] += ua.w * wv[i];
            a[4] += ub.x * wv[i]; a[5] += ub.y * wv[i];
            a[6] += ub.z * wv[i]; a[7] += ub.w * wv[i];
        }
    }
#pragma unroll
    for (int j = 0; j < 8; ++j)
        gpart[((size_t)(b0 + j) * NCH + ce) * D + d] = a[j];
}

// ---------------- K2: SINGLE-PASS online-softmax read. Grid 256 x 1024.
// kb[b] is read ONCE (was twice): per 16-col tile held in LDS we compute
// rai[16] (block reduce), then online-update m/Z and a per-thread output
// accumulator from the SAME tile. Double-buffered LDS; next tile's loads
// issue at phase start and land at phase end (HBM latency hidden under the
// two compute phases). Pad-17 LDS stride makes every access <=2-way bank
// aliasing (free, m136). Tail tile (4 cols) exact via -1e30 logit sentinels.
__global__ __launch_bounds__(1024, 1) void k_online(
    const float* __restrict__ kb, const float* __restrict__ gpart,
    const float* __restrict__ mem, const float* __restrict__ ctrl,
    const float* __restrict__ w_attn, float* __restrict__ out) {
    __shared__ float tile[2][D][TC + 1];   // 69.6 KB
    __shared__ float pr[TC][65];           // 4.2 KB
    __shared__ float rai_t[TC];
    __shared__ float p_s[D];               // 2 KB
    __shared__ float oa[2][D];             // 4 KB
    __shared__ float Zs[2];
    const int b = blockIdx.x;
    const int t = threadIdx.x;
    const float* base = kb + (size_t)b * D * S;

    // load mapping: thread -> rows (ld_d, ld_d+256), 64B col-segment
    const int ld_d = t >> 2, ld_jq = t & 3;
    const int col_lo = 4 * ld_jq;

    // prologue: issue tile-0 loads (always in range: col_lo <= 12)
    float4 v0 = *(const float4*)(base + (size_t)ld_d * S + col_lo);
    float4 v1 = *(const float4*)(base + (size_t)(ld_d + 256) * S + col_lo);

    // p head: p[d] = mem*g + u  (b_concat softmax-shift-invariant, dropped)
    if (t < D) {
        float s = 0.f;
#pragma unroll
        for (int ce = 0; ce < NCH; ++ce)
            s += gpart[((size_t)b * NCH + ce) * D + t];
        p_s[t] = mem[(size_t)b * D + t] * s +
                 ctrl[(size_t)b * D + t] * w_attn[t];
    }

    // stage tile 0
    tile[0][ld_d][col_lo + 0] = v0.x; tile[0][ld_d][col_lo + 1] = v0.y;
    tile[0][ld_d][col_lo + 2] = v0.z; tile[0][ld_d][col_lo + 3] = v0.w;
    tile[0][ld_d + 256][col_lo + 0] = v1.x;
    tile[0][ld_d + 256][col_lo + 1] = v1.y;
    tile[0][ld_d + 256][col_lo + 2] = v1.z;
    tile[0][ld_d + 256][col_lo + 3] = v1.w;
    __syncthreads();

    const int col = t & 15, dseg = t >> 4;   // (b): 16 cols x 64 d-segs
    const int wvx = t >> 6, l = t & 63;      // reduce: wave per col
    const int dow = t >> 1, sh = t & 1;      // (d): 512 d x 2 col-halves

    float mrun = -1e30f, Zrun = 0.f, oacc = 0.f;

    for (int j = 0; j < NT; ++j) {
        const int cur = j & 1;
        // issue loads for tile j+1 (land ~2 phases later)
        float4 u0 = {0.f, 0.f, 0.f, 0.f}, u1 = {0.f, 0.f, 0.f, 0.f};
        if (j + 1 < NT) {
            const int c0 = (j + 1) * TC + col_lo;
            if (c0 + 3 < S) {   // tail tile: only jq==0 valid, rest zero
                u0 = *(const float4*)(base + (size_t)ld_d * S + c0);
                u1 = *(const float4*)(base + (size_t)(ld_d + 256) * S + c0);
            }
        }
        // logits partial: thread (col, dseg) sums 8 d's
        float a = 0.f;
#pragma unroll
        for (int i = 0; i < 8; ++i)
            a += p_s[dseg * 8 + i] * tile[cur][dseg * 8 + i][col];
        pr[col][dseg] = a;
        __syncthreads();
        // reduce: wave wvx owns column wvx
        {
            float vs = pr[wvx][l];
#pragma unroll
            for (int o = 1; o < 64; o <<= 1) vs += __shfl_xor(vs, o, 64);
            if (l == 0)
                rai_t[wvx] = (j * TC + wvx < S) ? vs : -1e30f;
        }
        __syncthreads();
        // online softmax update (redundant per thread, deterministic)
        float mt = rai_t[0];
#pragma unroll
        for (int i = 1; i < TC; ++i) mt = fmaxf(mt, rai_t[i]);
        const float mnew = fmaxf(mrun, mt);
        const float f = __expf(mrun - mnew);   // 0 on first tile (underflow)
        float wexp[8];
        float zadd = 0.f;
#pragma unroll
        for (int i = 0; i < 8; ++i) {
            wexp[i] = __expf(rai_t[sh * 8 + i] - mnew);
            zadd += wexp[i];
        }
        Zrun = Zrun * f + zadd;
        oacc *= f;
#pragma unroll
        for (int i = 0; i < 8; ++i)
            oacc += wexp[i] * tile[cur][dow][sh * 8 + i];
        mrun = mnew;
        // stage tile j+1 into the other buffer (safe: all threads passed
        // this iteration's barriers, so prior reads of buf cur^1 are done)
        if (j + 1 < NT) {
            const int nb = cur ^ 1;
            tile[nb][ld_d][col_lo + 0] = u0.x;
            tile[nb][ld_d][col_lo + 1] = u0.y;
            tile[nb][ld_d][col_lo + 2] = u0.z;
            tile[nb][ld_d][col_lo + 3] = u0.w;
            tile[nb][ld_d + 256][col_lo + 0] = u1.x;
            tile[nb][ld_d + 256][col_lo + 1] = u1.y;
            tile[nb][ld_d + 256][col_lo + 2] = u1.z;
            tile[nb][ld_d + 256][col_lo + 3] = u1.w;
        }
        __syncthreads();
    }

    // combine column-halves and normalize
    oa[sh][dow] = oacc;
    if (t == 0) Zs[0] = Zrun;
    if (t == 1) Zs[1] = Zrun;
    __syncthreads();
    if (t < D)
        out[(size_t)b * D + t] = (oa[0][t] + oa[1][t]) / (Zs[0] + Zs[1]);
}

extern "C" void kernel_launch(void* const* d_in, const int* in_sizes, int n_in,
                              void* d_out, int out_size, void* d_ws, size_t ws_size,
                              hipStream_t stream) {
    const float* mem  = (const float*)d_in[0];  // [B, d]
    const float* ctrl = (const float*)d_in[1];  // [B, d]
    const float* kb   = (const float*)d_in[2];  // [B, d, S]
    const float* W    = (const float*)d_in[3];  // [d, d]
    // d_in[4] = b_concat: softmax-shift-invariant, unused
    const float* wat  = (const float*)d_in[5];  // [d]
    float* out = (float*)d_out;                 // [B, d]

    float* gpart = (float*)d_ws;                // B*8*D*4 = 4 MB

    k_gemm2 <<<512, 256,  0, stream>>>(ctrl, wat, W, gpart);
    k_online<<<B,   1024, 0, stream>>>(kb, gpart, mem, ctrl, wat, out);
}